// Round 1
// 68.110 us; speedup vs baseline: 1.0125x; 1.0125x over previous
//
#include <hip/hip_runtime.h>

// ForceThresholdCost, round 3: single fused kernel.
//
// Algebra (k_c is all-1000):
//   w[k]  = 1000 * sum_c (sum_i normals[c,i]) * (sum_j jac[c,j,k])   (k<7)
//   bias  = sum_c forces[c] - sum_k w[k]*start[k]
//   out[n] = (bias + sum_k w[k]*state[n,k]) > 3 ? 10000 : 0
//
// Round-2 structure was setup-kernel -> main-kernel, two serial launches.
// rocprof showed both kernels tiny (<40us, below the harness's own 40us
// poison fills); residual cost is launch latency + serialization.
// Fix: every WAVE redundantly recomputes the 64-contact reduction
// (normals/jac/forces = 6.6KB, L1/L2-hot after the first wave) with the
// IDENTICAL fp64 butterfly order as round 2 -> bit-identical w/bias ->
// no boundary flips at the fi>3 discontinuity.
// The 7 float4 state loads are issued BEFORE the reduction so HBM latency
// hides under the ~500-cycle fp64 shuffle chain.

#define FTC_D 7

__global__ __launch_bounds__(256) void ftc_fused_kernel(
    const float* __restrict__ start_state,   // [7]
    const float* __restrict__ state_batch,   // [ntot*7]
    const float* __restrict__ normals,       // [64*3]
    const float* __restrict__ jac,           // [64*3*7]
    const float* __restrict__ forces,        // [64]
    float* __restrict__ out,                 // [ntot]
    int nquad)                               // ntot/4
{
    const int t = blockIdx.x * 256 + threadIdx.x;
    const bool active = (t < nquad);

    // ---- issue the 4-row state load first (7x float4 = 112B/thread) ----
    float v[28];
    float4* vv = (float4*)v;
    if (active) {
        const float4* p = (const float4*)(state_batch + (size_t)t * 28);
        #pragma unroll
        for (int j = 0; j < 7; ++j) vv[j] = p[j];
    }

    // ---- per-wave redundant setup reduction (lane = contact index) ----
    const int c = threadIdx.x & 63;          // 0..63, one lane per contact
    double sn = (double)normals[c * 3 + 0]
              + (double)normals[c * 3 + 1]
              + (double)normals[c * 3 + 2];
    double vals[8];
    #pragma unroll
    for (int k = 0; k < FTC_D; ++k) {
        double tk = (double)jac[c * 21 + 0 * 7 + k]
                  + (double)jac[c * 21 + 1 * 7 + k]
                  + (double)jac[c * 21 + 2 * 7 + k];
        vals[k] = 1000.0 * sn * tk;
    }
    vals[7] = (double)forces[c];

    // 64-lane butterfly, 6 steps x 8 doubles — same order as round 2,
    // so the result is bit-identical in every lane of every wave.
    #pragma unroll
    for (int off = 32; off > 0; off >>= 1) {
        #pragma unroll
        for (int k = 0; k < 8; ++k)
            vals[k] += __shfl_xor(vals[k], off, 64);
    }

    double bias = vals[7];
    #pragma unroll
    for (int k = 0; k < FTC_D; ++k)
        bias -= vals[k] * (double)start_state[k];

    // ---- fp64 dot + threshold + float4 store ----
    if (active) {
        float4 o;
        float* ov = &o.x;
        #pragma unroll
        for (int r = 0; r < 4; ++r) {
            const float* s = v + r * 7;
            double fi = bias;
            fi = fma((double)s[0], vals[0], fi);
            fi = fma((double)s[1], vals[1], fi);
            fi = fma((double)s[2], vals[2], fi);
            fi = fma((double)s[3], vals[3], fi);
            fi = fma((double)s[4], vals[4], fi);
            fi = fma((double)s[5], vals[5], fi);
            fi = fma((double)s[6], vals[6], fi);
            ov[r] = (fi > 3.0) ? 10000.0f : 0.0f;
        }
        ((float4*)out)[t] = o;
    }
}

extern "C" void kernel_launch(void* const* d_in, const int* in_sizes, int n_in,
                              void* d_out, int out_size, void* d_ws, size_t ws_size,
                              hipStream_t stream) {
    const float* start_state = (const float*)d_in[0];  // (1,7)
    const float* state_batch = (const float*)d_in[1];  // (N,H,7)
    const float* normals     = (const float*)d_in[2];  // (64,3)
    const float* jac         = (const float*)d_in[3];  // (64,3,7)
    const float* forces      = (const float*)d_in[4];  // (64,)
    float* out = (float*)d_out;

    int ntot  = in_sizes[1] / FTC_D;                   // N*H = 262144
    int nquad = ntot / 4;                              // 65536 (ntot % 4 == 0)
    int grid  = (nquad + 255) / 256;                   // 256 blocks -> 1/CU

    ftc_fused_kernel<<<grid, 256, 0, stream>>>(
        start_state, state_batch, normals, jac, forces, out, nquad);
}